// Round 12
// baseline (1215.778 us; speedup 1.0000x reference)
//
#include <hip/hip_runtime.h>

// NCC forward: X,Y (16,32,64,24) fp32, PS=5, D=2, EPS=0.01
// out[blk*184320 + (yo*24+i)*1536 + p],  p = h*24+x, blk = b*32+c
//   = (cross - Em(h,x)*SF(h+yo,i)) * IE(h,x) * IF(h+yo,i)
// cross = sum_{dy,dx} Xp[h+dy][x+dx] * Yp[h+yo+dy][i+dx]
//
// R11: occupancy-first. Block = 256 thr = 4 waves; grid = 1536 (3 p-tiles x
// 512 channels) -> 6 blocks/CU, ALL blocks resident, zero tail.
// yo is an OUTER PHASE (5 phases): at fixed yo the Y register window is only
// yw[5][5]=25 regs -> total live ~72 regs, launch_bounds(256,6) cap 85 ->
// 24 waves/CU (vs 18 in R5/R9). Thread owns p=p0+2*tid, p+1 (x even, in-row);
// per phase sweeps i 0..23 with mod-5 compile-time col slots; float2 stores;
// block writes each (yo,i)-plane slice in perfectly ascending order.
// Y staged col-major (stride 32) in parity-shifted duplicate copies so the
// 5-row column roll is b64+b64+b32 for either parity of (h+yo).

#define NT 256

template<int K>
__device__ __forceinline__ void step_i(
    int i, int js,
    const float* __restrict__ pbY,   // col-major stride 32; row j0 of col c at pbY[c*32]
    const float* __restrict__ sFI,
    const float (&Xw)[5][6], float (&yw)[5][5],
    float Em0, float IE0, float Em1, float IE1,
    float* __restrict__ outP)        // outC + p + yo*24*1536
{
    // roll in col i+4, rows j0..j0+4: b64, b64, b32
    const float* q = pbY + (i + 4) * 32;
    float2 a = *(const float2*)q;
    float2 b = *(const float2*)(q + 2);
    float  e = q[4];
    constexpr int s4 = (K + 4) % 5;
    yw[0][s4] = a.x; yw[1][s4] = a.y; yw[2][s4] = b.x; yw[3][s4] = b.y; yw[4][s4] = e;

    // cross for 2 x-positions, one yo: 50 FMA (2 partial chains each)
    float c0a = 0.f, c0b = 0.f, c1a = 0.f, c1b = 0.f;
    #pragma unroll
    for (int dy = 0; dy < 5; ++dy) {
        #pragma unroll
        for (int dx = 0; dx < 5; ++dx) {
            const float yv = yw[dy][(K + dx) % 5];
            if (dx & 1) { c0b = fmaf(Xw[dy][dx], yv, c0b); c1b = fmaf(Xw[dy][dx + 1], yv, c1b); }
            else        { c0a = fmaf(Xw[dy][dx], yv, c0a); c1a = fmaf(Xw[dy][dx + 1], yv, c1a); }
        }
    }

    float2 f = *(const float2*)&sFI[(i * 26 + js) * 2];   // (SF, 1/Fs) at (i, h+yo)
    float2 v;
    v.x = fmaf(-Em0, f.x, c0a + c0b) * (IE0 * f.y);
    v.y = fmaf(-Em1, f.x, c1a + c1b) * (IE1 * f.y);
    *(float2*)(outP + (size_t)i * 1536) = v;
}

__global__ __launch_bounds__(NT, 6)
void ncc_kernel(const float* __restrict__ X, const float* __restrict__ Y,
                float* __restrict__ out)
{
    __shared__ __align__(16) float sXp[26 * 28];      // X rows hmin-2..hmin+23, cols -2..25
    __shared__ __align__(16) float sYe[28 * 32];      // Y col-major [c][jy], jy = Yrow-(hmin-4), rows 0..30
    __shared__ __align__(16) float sYo[28 * 32];      // shifted copy: [c*32 + jy-1] = row jy
    __shared__ __align__(16) float sFI[24 * 26 * 2];  // (SF, 1/Fs) per (i, js), stat row = hmin+js

    const int tid  = threadIdx.x;
    const int bid  = blockIdx.x;
    const int tile = bid >> 9;             // 0..2
    const int blk  = bid & 511;            // b*32 + c
    const int p0   = tile * 512;
    const int hmin = (tile == 0) ? 0 : (tile == 1 ? 21 : 42);

    const float* Xc = X + (size_t)blk * 1536;
    const float* Yc = Y + (size_t)blk * 1536;
    float* outC = out + (size_t)blk * 184320;

    // ---- Phase A: stage ----
    for (int idx = tid; idx < 26 * 28; idx += NT) {
        int jx = idx / 28, cc = idx - jx * 28;
        int hh = hmin - 2 + jx, ww = cc - 2;
        float v = 0.f;
        if ((unsigned)hh < 64u && (unsigned)ww < 24u) v = Xc[hh * 24 + ww];
        sXp[idx] = v;
    }
    for (int idx = tid; idx < 31 * 28; idx += NT) {
        int jy = idx / 28, cc = idx - jy * 28;
        int hh = hmin - 4 + jy, ww = cc - 2;
        float v = 0.f;
        if ((unsigned)hh < 64u && (unsigned)ww < 24u) v = Yc[hh * 24 + ww];
        sYe[cc * 32 + jy] = v;
        if (jy > 0) sYo[cc * 32 + jy - 1] = v;
    }
    __syncthreads();

    // ---- Phase B: Y patch stats; stat row s = hmin + js (= h+yo), Yp rows s..s+4 ----
    for (int idx = tid; idx < 24 * 26; idx += NT) {
        int ii = idx / 26, js = idx - ii * 26;
        float s = 0.f, s2 = 0.f;
        #pragma unroll
        for (int dx = 0; dx < 5; ++dx)
            #pragma unroll
            for (int dy = 0; dy < 5; ++dy) {
                float v = sYe[(ii + dx) * 32 + js + dy];
                s += v; s2 = fmaf(v, v, s2);
            }
        float var = fmaxf((s2 - s * s * 0.04f) * (1.f / 24.f), 0.f);
        sFI[idx * 2]     = s;                          // SF
        sFI[idx * 2 + 1] = 1.f / (sqrtf(var) + 0.01f); // 1/Fs
    }
    __syncthreads();

    // ---- Phase C setup: thread owns p, p+1 ----
    const int p  = p0 + 2 * tid;
    const int h  = p / 24;
    const int x  = p - h * 24;             // even
    const int jh = h - hmin;               // 0..21

    float Xw[5][6];                         // Xp rows h..h+4, cols x..x+5
    #pragma unroll
    for (int dy = 0; dy < 5; ++dy)
        #pragma unroll
        for (int c = 0; c < 6; ++c)
            Xw[dy][c] = sXp[(jh + dy) * 28 + x + c];

    float Em0, IE0, Em1, IE1;               // in-register X patch stats
    {
        float colS[6], colQ[6];
        #pragma unroll
        for (int c = 0; c < 6; ++c) {
            float s = 0.f, s2 = 0.f;
            #pragma unroll
            for (int dy = 0; dy < 5; ++dy) {
                float v = Xw[dy][c];
                s += v; s2 = fmaf(v, v, s2);
            }
            colS[c] = s; colQ[c] = s2;
        }
        float s0  = colS[0] + colS[1] + colS[2] + colS[3] + colS[4];
        float q0  = colQ[0] + colQ[1] + colQ[2] + colQ[3] + colQ[4];
        float s1  = colS[1] + colS[2] + colS[3] + colS[4] + colS[5];
        float q1  = colQ[1] + colQ[2] + colQ[3] + colQ[4] + colQ[5];
        float v0 = fmaxf((q0 - s0 * s0 * 0.04f) * (1.f / 24.f), 0.f);
        float v1 = fmaxf((q1 - s1 * s1 * 0.04f) * (1.f / 24.f), 0.f);
        Em0 = s0 * 0.04f; IE0 = 1.f / (25.f * (sqrtf(v0) + 0.01f));
        Em1 = s1 * 0.04f; IE1 = 1.f / (25.f * (sqrtf(v1) + 0.01f));
    }

    // ---- Phase C: 5 yo-phases x 24 i-steps ----
    #pragma unroll 1
    for (int yo = 0; yo < 5; ++yo) {
        const int js = jh + yo;            // stat row index
        const int j0 = js;                 // Y window top: local row (h+yo) - hmin
        // parity-aligned base: pbY[c*32 + dr] = Y local row j0+dr of col c
        const float* pbY = (j0 & 1) ? (sYo + (j0 - 1)) : (sYe + j0);
        float* outP = outC + p + (size_t)yo * 24 * 1536;

        float yw[5][5];                    // rows j0..j0+4, rolling col slots
        #pragma unroll
        for (int c = 0; c < 4; ++c) {      // prefill cols 0..3 -> slots 0..3
            const float* q = pbY + c * 32;
            float2 a = *(const float2*)q;
            float2 b = *(const float2*)(q + 2);
            yw[0][c] = a.x; yw[1][c] = a.y; yw[2][c] = b.x; yw[3][c] = b.y;
            yw[4][c] = q[4];
        }

        #pragma unroll 1
        for (int t5 = 0; t5 < 20; t5 += 5) {
            step_i<0>(t5 + 0, js, pbY, sFI, Xw, yw, Em0, IE0, Em1, IE1, outP);
            step_i<1>(t5 + 1, js, pbY, sFI, Xw, yw, Em0, IE0, Em1, IE1, outP);
            step_i<2>(t5 + 2, js, pbY, sFI, Xw, yw, Em0, IE0, Em1, IE1, outP);
            step_i<3>(t5 + 3, js, pbY, sFI, Xw, yw, Em0, IE0, Em1, IE1, outP);
            step_i<4>(t5 + 4, js, pbY, sFI, Xw, yw, Em0, IE0, Em1, IE1, outP);
        }
        step_i<0>(20, js, pbY, sFI, Xw, yw, Em0, IE0, Em1, IE1, outP);
        step_i<1>(21, js, pbY, sFI, Xw, yw, Em0, IE0, Em1, IE1, outP);
        step_i<2>(22, js, pbY, sFI, Xw, yw, Em0, IE0, Em1, IE1, outP);
        step_i<3>(23, js, pbY, sFI, Xw, yw, Em0, IE0, Em1, IE1, outP);
    }
}

extern "C" void kernel_launch(void* const* d_in, const int* in_sizes, int n_in,
                              void* d_out, int out_size, void* d_ws, size_t ws_size,
                              hipStream_t stream) {
    const float* X = (const float*)d_in[0];
    const float* Y = (const float*)d_in[1];
    float* out = (float*)d_out;
    ncc_kernel<<<dim3(3 * 512), dim3(NT), 0, stream>>>(X, Y, out);
}

// Round 14
// 117.176 us; speedup vs baseline: 10.3756x; 10.3756x over previous
//
#include <hip/hip_runtime.h>

// NCC forward: X,Y (16,32,64,24) fp32, PS=5, D=2, EPS=0.01
// out[blk*184320 + (yo*24+i)*1536 + h*24 + x] =
//   (cross - Em(h,x)*SF(h+yo,i)) * IE(h,x) * IF(h+yo,i)
// cross = sum_{dy,dx} Xp[h+dy][x+dx] * Yp[h+yo+dy][i+dx]
//
// R9 launch identity (proven no-spill): 512 blocks x 576 thr = 9 waves;
// thread=(x,h); 3 h-tiles; launch_bounds(576,5) -> VGPR<=102 -> 2 blocks/CU
// = 18 waves/CU. Parity-shifted duplicate Y copies (col-major, stride 74)
// give aligned b64 rolls for both (h+yo) parities.
// R13 change: yo is an OUTER PHASE. At fixed yo the Y window is yw[5][5]
// (25 regs, -20 vs R9 -> strictly lower spill risk) and the i-sweep writes
// ONE output plane in ascending address order (coherent replacement for the
// nt-store gain measured in R12, which was incoherent with harness poison).

#define NT 576

template<int K>
__device__ __forceinline__ void step_i(
    int i, int js,
    const float2* __restrict__ pbY,   // parity-aligned; col c row j0+dr at pbY[c*37], dr<5
    const float* __restrict__ sFI,
    const float (&Xw)[5][5], float (&yw)[5][5],
    float Em, float IE, float* __restrict__ outP)
{
    // roll in Yp column i+4, rows j0..j0+4: b64, b64, b32
    const float2* q = pbY + (i + 4) * 37;
    float2 a = q[0], b = q[1];
    float  e = ((const float*)q)[4];
    constexpr int s4 = (K + 4) % 5;
    yw[0][s4] = a.x; yw[1][s4] = a.y; yw[2][s4] = b.x; yw[3][s4] = b.y; yw[4][s4] = e;

    // cross for one yo: 25 FMA in two partial chains
    float ca = 0.f, cb = 0.f;
    #pragma unroll
    for (int dy = 0; dy < 5; ++dy) {
        #pragma unroll
        for (int dx = 0; dx < 5; ++dx) {
            const float yv = yw[dy][(K + dx) % 5];
            if (dx & 1) cb = fmaf(Xw[dy][dx], yv, cb);
            else        ca = fmaf(Xw[dy][dx], yv, ca);
        }
    }

    // (SF, 1/Fs) at (i, h+yo): one aligned b64
    float2 f = *(const float2*)&sFI[i * 136 + js * 2];
    float v = fmaf(-Em, f.x, ca + cb) * (IE * f.y);
    outP[(size_t)i * 1536] = v;
}

__global__ __launch_bounds__(NT, 5)
void ncc_kernel(const float* __restrict__ X, const float* __restrict__ Y,
                float* __restrict__ out)
{
    __shared__ __align__(16) float sXp[68 * 28];      // Xp row-major, rows 0..67
    __shared__ __align__(16) float sYe[28 * 74];      // Yp col-major [c][r], stride 74
    __shared__ __align__(16) float sYo[28 * 74];      // shifted: [c*74 + r-1] = Yp[c][r]
    __shared__ __align__(16) float sMI[64 * 24 * 2];  // (Em, IE) per (h,x)
    __shared__ __align__(16) float sFI[24 * 136];     // (SF, 1/Fs) interleaved [i][r]

    const int tid = threadIdx.x;
    const int blk = blockIdx.x;            // = b*32 + c
    const float* Xc = X + (size_t)blk * 1536;
    const float* Yc = Y + (size_t)blk * 1536;
    float* outC = out + (size_t)blk * 184320;

    // ---- Phase A: stage padded inputs (Y into both parity copies) ----
    for (int idx = tid; idx < 68 * 28; idx += NT) {
        int r = idx / 28, cc = idx - r * 28;
        int hh = r - 2, ww = cc - 2;
        float v = 0.f;
        if ((unsigned)hh < 64u && (unsigned)ww < 24u) v = Xc[hh * 24 + ww];
        sXp[idx] = v;
    }
    for (int idx = tid; idx < 72 * 28; idx += NT) {
        int r = idx / 28, cc = idx - r * 28;
        int hh = r - 4, ww = cc - 2;
        float v = 0.f;
        if ((unsigned)hh < 64u && (unsigned)ww < 24u) v = Yc[hh * 24 + ww];
        sYe[cc * 74 + r] = v;
        if (r > 0) sYo[cc * 74 + r - 1] = v;
    }
    __syncthreads();

    // ---- Phase B: patch statistics ----
    for (int idx = tid; idx < 64 * 24; idx += NT) {          // X stats -> sMI
        int hl = idx / 24, xx = idx - hl * 24;
        float s = 0.f, s2 = 0.f;
        #pragma unroll
        for (int dy = 0; dy < 5; ++dy)
            #pragma unroll
            for (int dx = 0; dx < 5; ++dx) {
                float v = sXp[(hl + dy) * 28 + xx + dx];
                s += v; s2 = fmaf(v, v, s2);
            }
        float var = fmaxf((s2 - s * s * 0.04f) * (1.f / 24.f), 0.f);
        sMI[idx * 2]     = s * 0.04f;                           // Em
        sMI[idx * 2 + 1] = 1.f / (25.f * (sqrtf(var) + 0.01f)); // 1/(25*Es)
    }
    for (int idx = tid; idx < 24 * 68; idx += NT) {          // Y stats -> sFI
        int ii = idx / 68, r = idx - ii * 68;
        float s = 0.f, s2 = 0.f;
        #pragma unroll
        for (int dx = 0; dx < 5; ++dx)
            #pragma unroll
            for (int dy = 0; dy < 5; ++dy) {
                float v = sYe[(ii + dx) * 74 + r + dy];
                s += v; s2 = fmaf(v, v, s2);
            }
        float var = fmaxf((s2 - s * s * 0.04f) * (1.f / 24.f), 0.f);
        int be = ii * 136 + r * 2;
        sFI[be]     = s;                                 // SF (patch sum)
        sFI[be + 1] = 1.f / (sqrtf(var) + 0.01f);        // 1/Fs
    }
    __syncthreads();

    // ---- Phase C: 3 h-tiles x 5 yo-phases x 24 i-steps; thread = (x, h) ----
    const int x  = tid % 24;
    const int hl = tid / 24;

    #pragma unroll 1
    for (int ht = 0; ht < 3; ++ht) {
        const int h = ht * 24 + hl;
        if (h >= 64) break;               // wave-aligned (tid>=384 in tile 2)
        const int lo = h * 24 + x;

        float2 mi = *(const float2*)&sMI[lo * 2];
        const float Em = mi.x, IE = mi.y;

        float Xw[5][5];                   // X window, loaded once per tile
        #pragma unroll
        for (int dy = 0; dy < 5; ++dy)
            #pragma unroll
            for (int dx = 0; dx < 5; ++dx)
                Xw[dy][dx] = sXp[(h + dy) * 28 + x + dx];

        #pragma unroll 1
        for (int yo = 0; yo < 5; ++yo) {
            const int js = h + yo;        // Y window top row / stat row
            // parity-aligned base: pbY[c*37 (float2)] covers rows js..js+4 of col c
            const float2* pbY = (js & 1) ? (const float2*)sYo + ((js - 1) >> 1)
                                         : (const float2*)sYe + (js >> 1);
            float* outP = outC + (size_t)yo * 36864 + lo;

            float yw[5][5];               // rows js..js+4, rolling col slots
            #pragma unroll
            for (int c = 0; c < 4; ++c) { // prefill cols 0..3 -> slots 0..3
                const float2* q = pbY + c * 37;
                float2 a = q[0], b = q[1];
                yw[0][c] = a.x; yw[1][c] = a.y; yw[2][c] = b.x; yw[3][c] = b.y;
                yw[4][c] = ((const float*)q)[4];
            }

            #pragma unroll 1
            for (int t5 = 0; t5 < 20; t5 += 5) {
                step_i<0>(t5 + 0, js, pbY, sFI, Xw, yw, Em, IE, outP);
                step_i<1>(t5 + 1, js, pbY, sFI, Xw, yw, Em, IE, outP);
                step_i<2>(t5 + 2, js, pbY, sFI, Xw, yw, Em, IE, outP);
                step_i<3>(t5 + 3, js, pbY, sFI, Xw, yw, Em, IE, outP);
                step_i<4>(t5 + 4, js, pbY, sFI, Xw, yw, Em, IE, outP);
            }
            step_i<0>(20, js, pbY, sFI, Xw, yw, Em, IE, outP);
            step_i<1>(21, js, pbY, sFI, Xw, yw, Em, IE, outP);
            step_i<2>(22, js, pbY, sFI, Xw, yw, Em, IE, outP);
            step_i<3>(23, js, pbY, sFI, Xw, yw, Em, IE, outP);
        }
    }
}

extern "C" void kernel_launch(void* const* d_in, const int* in_sizes, int n_in,
                              void* d_out, int out_size, void* d_ws, size_t ws_size,
                              hipStream_t stream) {
    const float* X = (const float*)d_in[0];
    const float* Y = (const float*)d_in[1];
    float* out = (float*)d_out;
    ncc_kernel<<<dim3(16 * 32), dim3(NT), 0, stream>>>(X, Y, out);
}

// Round 15
// 104.340 us; speedup vs baseline: 11.6521x; 1.1230x over previous
//
#include <hip/hip_runtime.h>

// NCC forward: X,Y (16,32,64,24) fp32, PS=5, D=2, EPS=0.01
// out[blk*184320 + (yo*24+i)*1536 + h*24 + x] =
//   (cross - Em(h,x)*SF(h+yo,i)) * IE(h,x) * IF(h+yo,i)
// cross = sum_{dy,dx} Xp[h+dy][x+dx] * Yp[h+yo+dy][i+dx]
//
// FINAL (R9 verbatim, proven 104.6us): 512 blocks x 576 thr = 9 waves;
// thread=(x,h); 3 h-tiles; sweep i with mod-5 compile-time col slots;
// launch_bounds(576,5) -> VGPR<=102 -> 2 blocks/CU = 18 waves/CU.
// Parity-shifted duplicate copies of Y (col-major, stride 74) and of the
// (SF,1/Fs) table give aligned vector reads for both h parities:
// roll = 5x ds_read_b64, stats = 3x ds_read_b128.
// Session findings: latency-bound at max non-spilling occupancy; store
// pattern/order, LDS diet, VALU diet all flat; occupancy down -24%, up =
// spill cliff; nt stores -7% but incoherent with harness poison writeback.

#define NT 576

template<int K>
__device__ __forceinline__ void step_i(
    int i,
    const float2* __restrict__ pbY, const float4* __restrict__ pbF,
    const float (&Xw)[5][5], float (&yw)[9][5],
    float Em, float IE, float* __restrict__ outT)
{
    // roll in Yp column i+4, rows h..h+8: 5x b64 (10th float unused)
    const float2* q = pbY + (i + 4) * 37;
    float2 t0 = q[0], t1 = q[1], t2 = q[2], t3 = q[3], t4 = q[4];
    constexpr int s4 = (K + 4) % 5;
    yw[0][s4] = t0.x; yw[1][s4] = t0.y;
    yw[2][s4] = t1.x; yw[3][s4] = t1.y;
    yw[4][s4] = t2.x; yw[5][s4] = t2.y;
    yw[6][s4] = t3.x; yw[7][s4] = t3.y;
    yw[8][s4] = t4.x;

    // cross for 5 yo: 125 FMA, all register operands
    float cr[5] = {0.f, 0.f, 0.f, 0.f, 0.f};
    #pragma unroll
    for (int dy = 0; dy < 5; ++dy) {
        #pragma unroll
        for (int dx = 0; dx < 5; ++dx) {
            const float xv = Xw[dy][dx];
            #pragma unroll
            for (int yo = 0; yo < 5; ++yo)
                cr[yo] = fmaf(xv, yw[dy + yo][(K + dx) % 5], cr[yo]);
        }
    }

    // (SF,1/Fs) rows h..h+4 at col i: 3x b128 (6th row unused)
    const float4* fq = pbF + i * 34;
    float4 f0 = fq[0], f1 = fq[1], f2 = fq[2];
    const float sf[5] = {f0.x, f0.z, f1.x, f1.z, f2.x};
    const float iv[5] = {f0.y, f0.w, f1.y, f1.w, f2.y};
    #pragma unroll
    for (int yo = 0; yo < 5; ++yo) {
        float v = fmaf(-Em, sf[yo], cr[yo]) * (IE * iv[yo]);
        outT[(size_t)(yo * 24 + i) * 1536] = v;
    }
}

__global__ __launch_bounds__(NT, 5)
void ncc_kernel(const float* __restrict__ X, const float* __restrict__ Y,
                float* __restrict__ out)
{
    __shared__ __align__(16) float sXp[68 * 28];   // Xp row-major, rows 0..67
    __shared__ __align__(16) float sYe[28 * 74];   // Yp col-major [c][r], stride 74
    __shared__ __align__(16) float sYo[28 * 74];   // same, shifted: [c*74 + r-1] = Yp[c][r]
    __shared__ __align__(16) float sMI[64 * 24 * 2]; // (Em, IE) per (h,x)
    __shared__ __align__(16) float sFe[24 * 136];  // (SF,IF) interleaved [i][r], stride 136
    __shared__ __align__(16) float sFo[24 * 136];  // shifted copy: [i*136+(r-1)*2] = row r

    const int tid = threadIdx.x;
    const int blk = blockIdx.x;            // = b*32 + c
    const float* Xc = X + (size_t)blk * 1536;
    const float* Yc = Y + (size_t)blk * 1536;
    float* outC = out + (size_t)blk * 184320;

    // ---- Phase A: stage padded inputs (Y into both parity copies) ----
    for (int idx = tid; idx < 68 * 28; idx += NT) {
        int r = idx / 28, cc = idx - r * 28;
        int hh = r - 2, ww = cc - 2;
        float v = 0.f;
        if ((unsigned)hh < 64u && (unsigned)ww < 24u) v = Xc[hh * 24 + ww];
        sXp[idx] = v;
    }
    for (int idx = tid; idx < 72 * 28; idx += NT) {
        int r = idx / 28, cc = idx - r * 28;
        int hh = r - 4, ww = cc - 2;
        float v = 0.f;
        if ((unsigned)hh < 64u && (unsigned)ww < 24u) v = Yc[hh * 24 + ww];
        sYe[cc * 74 + r] = v;
        if (r > 0) sYo[cc * 74 + r - 1] = v;
    }
    __syncthreads();

    // ---- Phase B: patch statistics ----
    for (int idx = tid; idx < 64 * 24; idx += NT) {          // X stats -> sMI
        int hl = idx / 24, xx = idx - hl * 24;
        float s = 0.f, s2 = 0.f;
        #pragma unroll
        for (int dy = 0; dy < 5; ++dy)
            #pragma unroll
            for (int dx = 0; dx < 5; ++dx) {
                float v = sXp[(hl + dy) * 28 + xx + dx];
                s += v; s2 = fmaf(v, v, s2);
            }
        float var = fmaxf((s2 - s * s * 0.04f) * (1.f / 24.f), 0.f);
        sMI[idx * 2]     = s * 0.04f;                        // Em
        sMI[idx * 2 + 1] = 1.f / (25.f * (sqrtf(var) + 0.01f)); // 1/(25*Es)
    }
    for (int idx = tid; idx < 24 * 68; idx += NT) {          // Y stats -> sFe/sFo
        int ii = idx / 68, r = idx - ii * 68;
        float s = 0.f, s2 = 0.f;
        #pragma unroll
        for (int dx = 0; dx < 5; ++dx)
            #pragma unroll
            for (int dy = 0; dy < 5; ++dy) {
                float v = sYe[(ii + dx) * 74 + r + dy];
                s += v; s2 = fmaf(v, v, s2);
            }
        float var = fmaxf((s2 - s * s * 0.04f) * (1.f / 24.f), 0.f);
        float invf = 1.f / (sqrtf(var) + 0.01f);
        int be = ii * 136 + r * 2;
        sFe[be] = s; sFe[be + 1] = invf;
        if (r > 0) { int bo = ii * 136 + (r - 1) * 2; sFo[bo] = s; sFo[bo + 1] = invf; }
    }
    __syncthreads();

    // ---- Phase C: 3 h-tiles x 24 i-steps; thread = (x, h) ----
    const int x  = tid % 24;
    const int hl = tid / 24;

    #pragma unroll 1
    for (int ht = 0; ht < 3; ++ht) {
        const int h = ht * 24 + hl;
        if (h >= 64) break;               // wave-aligned (tid>=384 in tile 2)
        const int lo = h * 24 + x;

        float2 mi = *(const float2*)&sMI[lo * 2];
        const float Em = mi.x, IE = mi.y;

        // parity-selected aligned base pointers (setup-only cost)
        const float2* pbY = (h & 1) ? (const float2*)sYo + ((h - 1) >> 1)
                                    : (const float2*)sYe + (h >> 1);
        const float4* pbF = (h & 1) ? (const float4*)sFo + ((h - 1) >> 1)
                                    : (const float4*)sFe + (h >> 1);

        float Xw[5][5];                   // X window, loaded once per tile
        #pragma unroll
        for (int dy = 0; dy < 5; ++dy)
            #pragma unroll
            for (int dx = 0; dx < 5; ++dx)
                Xw[dy][dx] = sXp[(h + dy) * 28 + x + dx];

        float yw[9][5];                   // Yp rows h..h+8, rolling col slots
        #pragma unroll
        for (int c = 0; c < 4; ++c) {     // prefill cols 0..3 -> slots 0..3
            const float2* q = pbY + c * 37;
            float2 t0 = q[0], t1 = q[1], t2 = q[2], t3 = q[3], t4 = q[4];
            yw[0][c] = t0.x; yw[1][c] = t0.y;
            yw[2][c] = t1.x; yw[3][c] = t1.y;
            yw[4][c] = t2.x; yw[5][c] = t2.y;
            yw[6][c] = t3.x; yw[7][c] = t3.y;
            yw[8][c] = t4.x;
        }

        float* outT = outC + lo;

        #pragma unroll 1
        for (int t5 = 0; t5 < 20; t5 += 5) {
            step_i<0>(t5 + 0, pbY, pbF, Xw, yw, Em, IE, outT);
            step_i<1>(t5 + 1, pbY, pbF, Xw, yw, Em, IE, outT);
            step_i<2>(t5 + 2, pbY, pbF, Xw, yw, Em, IE, outT);
            step_i<3>(t5 + 3, pbY, pbF, Xw, yw, Em, IE, outT);
            step_i<4>(t5 + 4, pbY, pbF, Xw, yw, Em, IE, outT);
        }
        step_i<0>(20, pbY, pbF, Xw, yw, Em, IE, outT);
        step_i<1>(21, pbY, pbF, Xw, yw, Em, IE, outT);
        step_i<2>(22, pbY, pbF, Xw, yw, Em, IE, outT);
        step_i<3>(23, pbY, pbF, Xw, yw, Em, IE, outT);
    }
}

extern "C" void kernel_launch(void* const* d_in, const int* in_sizes, int n_in,
                              void* d_out, int out_size, void* d_ws, size_t ws_size,
                              hipStream_t stream) {
    const float* X = (const float*)d_in[0];
    const float* Y = (const float*)d_in[1];
    float* out = (float*)d_out;
    ncc_kernel<<<dim3(16 * 32), dim3(NT), 0, stream>>>(X, Y, out);
}